// Round 5
// baseline (2485.258 us; speedup 1.0000x reference)
//
#include <hip/hip_runtime.h>
#include <cstdio>
#include <cmath>
#include <cstdint>

// ---------------- problem constants ----------------
constexpr int BM = 512 * 104;       // 53248 rows
constexpr float BN_EPS = 1e-5f;

// ---------------- workspace layout (bytes) ----------------
constexpr size_t SZ_BF = (size_t)BM * 512 * 2;        // 54,525,952
constexpr size_t SZ_M5 = (size_t)5 * 512 * 512 * 4;   // 5,242,880
// overlay region inside YB0 (all dead before conv chain starts):
constexpr size_t OFF_YB0  = 0;
constexpr size_t OFF_XP   = 0;                         // X^1..X^8 / E0..E5
constexpr size_t OFF_MW   = OFF_XP + 8 * SZ_M5;        // 41,943,040
constexpr size_t OFF_ROWT = OFF_MW + SZ_M5;            // [5][64][512]
constexpr size_t OFF_COLS1= OFF_ROWT + 655360;
constexpr size_t OFF_COLS2= OFF_COLS1 + 655360;
constexpr size_t OFF_PIVA = OFF_COLS2 + 655360;
constexpr size_t OFF_PIVB = OFF_PIVA + 81920;
constexpr size_t OFF_RU   = OFF_PIVB + 81920;          // [5][64]
static_assert(OFF_RU + 2048 <= SZ_BF, "overlay overflow");
constexpr size_t OFF_YB1  = SZ_BF;
constexpr size_t OFF_WT2  = OFF_YB1 + SZ_BF;           // conv weights bf16 [4][3][co][ci]
constexpr size_t OFF_PJT  = OFF_WT2 + 6291456;
constexpr size_t OFF_F1T  = OFF_PJT + 1048576;
constexpr size_t OFF_G    = OFF_F1T + 1048576;
constexpr size_t OFF_POOL = OFF_G   + 1048576;
constexpr size_t OFF_Z    = OFF_POOL + 1048576;
constexpr size_t OFF_ST   = OFF_Z   + 1048576;         // fp64 stats [6][2][512]
constexpr size_t OFF_V    = OFF_ST  + 49152;           // V[5][8][512]
constexpr size_t OFF_WV   = OFF_V   + 81920;           // W[5][13][512]
constexpr size_t OFF_SVEC = OFF_WV  + 133120;          // s[104]+sbar
constexpr size_t WS_NEED  = OFF_SVEC + 512;

// ---------------- helpers ----------------
__device__ __forceinline__ float bf2f(unsigned short u) {
    union { uint32_t i; float f; } x; x.i = (uint32_t)u << 16; return x.f;
}
__device__ __forceinline__ unsigned short f2bf(float f) {
    union { float f; uint32_t i; } x; x.f = f;
    uint32_t r = x.i + 0x7FFFu + ((x.i >> 16) & 1u);
    return (unsigned short)(r >> 16);
}
typedef __bf16 bf16x8 __attribute__((ext_vector_type(8)));
typedef float  f32x4  __attribute__((ext_vector_type(4)));

__device__ __forceinline__ void gld16(const void* g, void* l) {
    __builtin_amdgcn_global_load_lds((const __attribute__((address_space(1))) uint32_t*)g,
                                     (__attribute__((address_space(3))) uint32_t*)l, 16, 0, 0);
}

// ============ pivoted 64x64 GJ inverse on LDS mat (stride 65) -> Pg ============
__device__ void inv_body(float* mat, float* Pg, int tid)
{
    __shared__ int perm[64];
    __shared__ int arr[64];
    __shared__ int pividx;
    __shared__ float fv[64];
    __shared__ float dv;
    for (int j = 0; j < 64; ++j) {
        if (tid < 64) {
            float v = (tid >= j) ? fabsf(mat[tid * 65 + j]) : -1.0f;
            int idx = tid;
#pragma unroll
            for (int off = 32; off; off >>= 1) {
                float ov = __shfl_down(v, off);
                int oi = __shfl_down(idx, off);
                if (ov > v) { v = ov; idx = oi; }
            }
            if (tid == 0) pividx = idx;
        }
        __syncthreads();
        int r = pividx;
        if (tid < 64) {
            if (r != j) {
                float tj = mat[j * 65 + tid], tr = mat[r * 65 + tid];
                mat[j * 65 + tid] = tr; mat[r * 65 + tid] = tj;
            }
            if (tid == 0) perm[j] = r;
        }
        __syncthreads();
        if (tid < 64) {
            float piv = mat[j * 65 + j];
            float d = 1.0f / piv;
            fv[tid] = mat[tid * 65 + j];
            mat[j * 65 + tid] = (tid == j) ? d : mat[j * 65 + tid] * d;
            if (tid == 0) dv = d;
        }
        __syncthreads();
        {
            int i = tid & 63, c0 = (tid >> 6) * 16;
            if (i != j) {
                float f = fv[i], dd = dv;
#pragma unroll
                for (int u = 0; u < 16; ++u) {
                    int c = c0 + u;
                    float val = mat[i * 65 + c] - f * mat[j * 65 + c];
                    if (c == j) val = -f * dd;
                    mat[i * 65 + c] = val;
                }
            }
        }
        __syncthreads();
    }
    if (tid == 0) {
        for (int c = 0; c < 64; ++c) arr[c] = c;
        for (int j = 63; j >= 0; --j) { int r = perm[j]; int t = arr[j]; arr[j] = arr[r]; arr[r] = t; }
    }
    __syncthreads();
    for (int it = 0; it < 16; ++it) {
        int idx = it * 256 + tid;
        int r = idx >> 6, c = idx & 63;
        Pg[r * 64 + c] = mat[r * 65 + arr[c]];
    }
}

// ============ front: conv-weights->bf16 | build X,S,COLS0,W0 | inv0 ============
__global__ __launch_bounds__(256) void k_front(
    const float* __restrict__ W, unsigned short* __restrict__ Wt2,
    const float* __restrict__ Aall, float* __restrict__ X, float* __restrict__ MW,
    float* __restrict__ COLS1, const float* __restrict__ Call, float* __restrict__ WV,
    float* __restrict__ PIVA)
{
    int bid = blockIdx.x, tid = threadIdx.x;
    if (bid < 2048) {
        int co = bid & 511, l = bid >> 9;
        const float* src = W + (long)(l * 512 + co) * 512 * 3;
        unsigned short* dst = Wt2 + (long)l * 3 * 262144 + ((long)co << 9);
#pragma unroll
        for (int q = 0; q < 2; ++q) {
            int ci = tid * 2 + q;
            dst[ci]          = f2bf(src[ci * 3 + 0]);
            dst[262144 + ci] = f2bf(src[ci * 3 + 1]);
            dst[524288 + ci] = f2bf(src[ci * 3 + 2]);
        }
        return;
    }
    if (bid < 7168) {
        long i = (long)(bid - 2048) * 256 + tid;
        float a = Aall[i];
        X[i] = 0.1f * a;
        int z = (int)(i >> 18);
        int rc = (int)(i & 262143);
        int r = rc >> 9, c = rc & 511;
        float mw = a + ((r == c) ? 0.001f : 0.0f);
        MW[i] = mw;
        if (c < 64) COLS1[(long)z * 32768 + r * 64 + c] = mw;
        if (i < 2560) WV[(i >> 9) * 6656 + (i & 511)] = Call[i];
        return;
    }
    {
        int z = bid - 7168;
        __shared__ float mat[64 * 65];
        for (int it = 0; it < 16; ++it) {
            int idx = it * 256 + tid;
            int r = idx >> 6, c = idx & 63;
            mat[r * 65 + c] = Aall[(long)z * 262144 + r * 512 + c] + ((r == c) ? 0.001f : 0.0f);
        }
        __syncthreads();
        inv_body(mat, PIVA + z * 4096, tid);
    }
}

// ============ packed batched 512^3 fp32 matmul: C = A*B, task table ============
struct MMT { long a[4], b[4], c[4]; };
__global__ __launch_bounds__(256) void k_mmP(const char* __restrict__ ws, MMT T)
{
    __shared__ float sm[2 * 32 * 68];
    float* As = sm;
    float* Bs = sm + 32 * 68;
    int task = blockIdx.z / 5, bz = blockIdx.z % 5;
    const float* A  = (const float*)(ws + T.a[task]) + (long)bz * 262144;
    const float* Bm = (const float*)(ws + T.b[task]) + (long)bz * 262144;
    float* C        = (float*)(ws + T.c[task]) + (long)bz * 262144;
    int m0 = blockIdx.x * 64, n0 = blockIdx.y * 64;
    int tid = threadIdx.x;
    int tx = tid & 15, ty = tid >> 4;
    float acc[4][4] = {};
    for (int k0 = 0; k0 < 512; k0 += 32) {
        __syncthreads();
#pragma unroll
        for (int it = 0; it < 2; ++it) {
            int s = it * 256 + tid;
            int mm = s >> 3, k4 = (s & 7) * 4;
            float4 v = *(const float4*)&A[(long)(m0 + mm) * 512 + k0 + k4];
            As[(k4 + 0) * 68 + mm] = v.x;
            As[(k4 + 1) * 68 + mm] = v.y;
            As[(k4 + 2) * 68 + mm] = v.z;
            As[(k4 + 3) * 68 + mm] = v.w;
        }
#pragma unroll
        for (int it = 0; it < 2; ++it) {
            int s = it * 256 + tid;
            int kk = s >> 4, n4 = (s & 15) * 4;
            *(float4*)&Bs[kk * 68 + n4] = *(const float4*)&Bm[(long)(k0 + kk) * 512 + n0 + n4];
        }
        __syncthreads();
#pragma unroll 8
        for (int kk = 0; kk < 32; ++kk) {
            float4 a = *(const float4*)&As[kk * 68 + ty * 4];
            float4 b = *(const float4*)&Bs[kk * 68 + tx * 4];
            float av[4] = {a.x, a.y, a.z, a.w};
            float bv[4] = {b.x, b.y, b.z, b.w};
#pragma unroll
            for (int i = 0; i < 4; ++i)
#pragma unroll
                for (int j = 0; j < 4; ++j)
                    acc[i][j] = fmaf(av[i], bv[j], acc[i][j]);
        }
    }
#pragma unroll
    for (int i = 0; i < 4; ++i) {
        long base = (long)(m0 + ty * 4 + i) * 512 + n0 + tx * 4;
        *(float4*)&C[base] = make_float4(acc[i][0], acc[i][1], acc[i][2], acc[i][3]);
    }
}

// ============ elementwise: E_k = A_bar^(2^k) - I = sum_p c[k][p] X^p ============
struct PolyC { float c[6][8]; };
__global__ void k_poly(float* __restrict__ XP, PolyC P)
{
    long i = (long)blockIdx.x * 256 + threadIdx.x;   // 1,310,720 total
    float x[8];
#pragma unroll
    for (int p = 0; p < 8; ++p) x[p] = XP[(long)p * 1310720 + i];
    float e[6];
#pragma unroll
    for (int k = 0; k < 6; ++k) {
        float s = 0.0f;
#pragma unroll
        for (int p = 0; p < 8; ++p) s = fmaf(P.c[k][p], x[p], s);
        e[k] = s;
    }
#pragma unroll
    for (int k = 0; k < 6; ++k) XP[(long)k * 1310720 + i] = e[k];
}

// ============ batched matvec (u = 0.1 * E0 * Bv) ============
__global__ void k_matvecA(const float* __restrict__ A, long sA,
                          const float* __restrict__ x, long sx,
                          float* __restrict__ y, long sy, float alpha)
{
    int row = blockIdx.x, z = blockIdx.y, lane = threadIdx.x;
    A += (long)z * sA; x += (long)z * sx; y += (long)z * sy;
    const float* ar = A + (long)row * 512;
    double acc = 0.0;
#pragma unroll
    for (int m = 0; m < 8; ++m) acc += (double)ar[lane + m * 64] * (double)x[lane + m * 64];
    for (int off = 32; off; off >>= 1) acc += __shfl_down(acc, off);
    if (lane == 0) y[row] = alpha * (float)acc;
}

// ============ GJ step 1: ROWT = inv(D_p) * M[pivrows, cols>p]; ru = inv(D_p)*u[piv] ============
__global__ __launch_bounds__(256) void k_rowscale(
    const float* __restrict__ MW, const float* __restrict__ PIVIc,
    const float* __restrict__ V0, float* __restrict__ ROWT, float* __restrict__ RU, int p)
{
    __shared__ float PivT[64 * 68];
    __shared__ float Bp[64 * 68];
    __shared__ float uL[64];
    int z = blockIdx.z, nIdx = blockIdx.x, tid = threadIdx.x;
    int pr = p * 64;
    MW += (long)z * 262144; PIVIc += (long)z * 4096; ROWT += (long)z * 32768;
    for (int it = 0; it < 16; ++it) {
        int idx = it * 256 + tid;
        int m = idx >> 6, k = idx & 63;
        PivT[k * 68 + m] = PIVIc[m * 64 + k];
    }
    if (nIdx == 7 - p) {      // u task
        if (tid < 64) uL[tid] = V0[(long)z * 4096 + pr + tid];
        __syncthreads();
        if (tid < 64) {
            float acc = 0.0f;
            for (int k = 0; k < 64; ++k) acc += PivT[k * 68 + tid] * uL[k];
            RU[z * 64 + tid] = acc;
        }
        return;
    }
    int n0 = (p + 1 + nIdx) * 64;
    {
        int r = tid >> 2, cb = (tid & 3) * 16;
#pragma unroll
        for (int u4 = 0; u4 < 4; ++u4)
            *(float4*)&Bp[r * 68 + cb + u4 * 4] = *(const float4*)&MW[(long)(pr + r) * 512 + n0 + cb + u4 * 4];
    }
    __syncthreads();
    int tx = tid & 15, ty = tid >> 4;
    float acc[4][4] = {};
#pragma unroll 8
    for (int k = 0; k < 64; ++k) {
        float4 a = *(const float4*)&PivT[k * 68 + ty * 4];
        float4 b = *(const float4*)&Bp[k * 68 + tx * 4];
        float av[4] = {a.x, a.y, a.z, a.w};
        float bv[4] = {b.x, b.y, b.z, b.w};
#pragma unroll
        for (int i = 0; i < 4; ++i)
#pragma unroll
            for (int j = 0; j < 4; ++j)
                acc[i][j] = fmaf(av[i], bv[j], acc[i][j]);
    }
#pragma unroll
    for (int i = 0; i < 4; ++i)
        *(float4*)&ROWT[(ty * 4 + i) * 512 + n0 + tx * 4] =
            make_float4(acc[i][0], acc[i][1], acc[i][2], acc[i][3]);
}

// ============ GJ step 2: eliminate; diag block runs next inverse ============
__global__ __launch_bounds__(256) void k_elim2(
    float* __restrict__ MW, const float* __restrict__ COLSc, float* __restrict__ COLSn,
    const float* __restrict__ ROWT, const float* __restrict__ RU,
    float* __restrict__ V0, float* __restrict__ PIVIn, int p)
{
    __shared__ float As[64 * 68];
    __shared__ float Bs[64 * 68];
    __shared__ float mat[64 * 65];
    __shared__ float ru[64];
    int z = blockIdx.z, tid = threadIdx.x;
    int m0 = blockIdx.x * 64, nIdx = blockIdx.y, pr = p * 64;
    MW += (long)z * 262144; COLSc += (long)z * 32768; COLSn += (long)z * 32768;
    ROWT += (long)z * 32768;
    bool isU = (nIdx == 7 - p);
    if (isU) {
        if (m0 == pr) {
            if (tid < 64) V0[(long)z * 4096 + pr + tid] = RU[z * 64 + tid];
            return;
        }
        if (tid < 64) ru[tid] = RU[z * 64 + tid];
        {
            int m = tid >> 2, kb = (tid & 3) * 16;
#pragma unroll
            for (int u4 = 0; u4 < 4; ++u4) {
                float4 v = *(const float4*)&COLSc[(m0 + m) * 64 + kb + u4 * 4];
                As[(kb + u4 * 4 + 0) * 68 + m] = v.x;
                As[(kb + u4 * 4 + 1) * 68 + m] = v.y;
                As[(kb + u4 * 4 + 2) * 68 + m] = v.z;
                As[(kb + u4 * 4 + 3) * 68 + m] = v.w;
            }
        }
        __syncthreads();
        if (tid < 64) {
            float acc = 0.0f;
            for (int k = 0; k < 64; ++k) acc += As[k * 68 + tid] * ru[k];
            V0[(long)z * 4096 + m0 + tid] -= acc;
        }
        return;
    }
    int n0 = (p + 1 + nIdx) * 64;
    if (m0 == pr) {       // pivot rows <- scaled panel
        for (int it = 0; it < 16; ++it) {
            int idx = it * 256 + tid;
            int r = idx >> 6, c = idx & 63;
            float v = ROWT[r * 512 + n0 + c];
            MW[(long)(pr + r) * 512 + n0 + c] = v;
            if (n0 == pr + 64) COLSn[(pr + r) * 64 + c] = v;
        }
        return;
    }
    {
        int m = tid >> 2, kb = (tid & 3) * 16;
#pragma unroll
        for (int u4 = 0; u4 < 4; ++u4) {
            float4 v = *(const float4*)&COLSc[(m0 + m) * 64 + kb + u4 * 4];
            As[(kb + u4 * 4 + 0) * 68 + m] = v.x;
            As[(kb + u4 * 4 + 1) * 68 + m] = v.y;
            As[(kb + u4 * 4 + 2) * 68 + m] = v.z;
            As[(kb + u4 * 4 + 3) * 68 + m] = v.w;
        }
        int r = tid >> 2, cb = (tid & 3) * 16;
#pragma unroll
        for (int u4 = 0; u4 < 4; ++u4)
            *(float4*)&Bs[r * 68 + cb + u4 * 4] = *(const float4*)&ROWT[r * 512 + n0 + cb + u4 * 4];
    }
    __syncthreads();
    int tx = tid & 15, ty = tid >> 4;
    float acc[4][4] = {};
#pragma unroll 8
    for (int k = 0; k < 64; ++k) {
        float4 a = *(const float4*)&As[k * 68 + ty * 4];
        float4 b = *(const float4*)&Bs[k * 68 + tx * 4];
        float av[4] = {a.x, a.y, a.z, a.w};
        float bv[4] = {b.x, b.y, b.z, b.w};
#pragma unroll
        for (int i = 0; i < 4; ++i)
#pragma unroll
            for (int j = 0; j < 4; ++j)
                acc[i][j] = fmaf(av[i], bv[j], acc[i][j]);
    }
    float out[4][4];
#pragma unroll
    for (int i = 0; i < 4; ++i) {
        long base = (long)(m0 + ty * 4 + i) * 512 + n0 + tx * 4;
        float4 oldv = *(const float4*)&MW[base];
        out[i][0] = oldv.x - acc[i][0];
        out[i][1] = oldv.y - acc[i][1];
        out[i][2] = oldv.z - acc[i][2];
        out[i][3] = oldv.w - acc[i][3];
        *(float4*)&MW[base] = make_float4(out[i][0], out[i][1], out[i][2], out[i][3]);
        if (n0 == pr + 64)
            *(float4*)&COLSn[(m0 + ty * 4 + i) * 64 + tx * 4] =
                make_float4(out[i][0], out[i][1], out[i][2], out[i][3]);
    }
    if (m0 == pr + 64 && nIdx == 0 && p < 7) {
#pragma unroll
        for (int i = 0; i < 4; ++i)
#pragma unroll
            for (int j = 0; j < 4; ++j)
                mat[(ty * 4 + i) * 65 + tx * 4 + j] = out[i][j];
        __syncthreads();
        inv_body(mat, PIVIn + (long)z * 4096, tid);
    }
}

// ============ merged V/W chain multi-task matvec (E-matrices, +beta*x) ============
struct VWT { long a[8]; long x[8]; long y[8]; float al[8]; float be[8]; int ty[8]; };
__global__ void k_vw(const char* __restrict__ ws, VWT T)
{
    int g = blockIdx.x, z = blockIdx.y, t = blockIdx.z;
    int lane = threadIdx.x;
    const float* A = (const float*)(ws + T.a[t]) + (long)z * 262144;
    int ty = T.ty[t];
    long vs = ty ? 6656 : 4096;
    const float* x = (const float*)(ws + T.x[t]) + (long)z * vs;
    float* yv = (float*)(ws + T.y[t]) + (long)z * vs;
    if (ty == 0) {
        float xm[8];
#pragma unroll
        for (int m = 0; m < 8; ++m) xm[m] = x[lane + m * 64];
        float alpha = T.al[t], beta = T.be[t];
        for (int r0 = 0; r0 < 64; ++r0) {
            int row = g * 64 + r0;
            const float* ar = A + (long)row * 512;
            double acc = 0.0;
#pragma unroll
            for (int m = 0; m < 8; ++m) acc += (double)ar[lane + m * 64] * (double)xm[m];
            for (int off = 32; off; off >>= 1) acc += __shfl_down(acc, off);
            if (lane == 0) yv[row] = alpha * (float)acc + beta * x[row];
        }
    } else {
        __shared__ float xl[512];
#pragma unroll
        for (int m = 0; m < 8; ++m) xl[lane + m * 64] = x[lane + m * 64];
        __syncthreads();
        int c = g * 64 + lane;
        double acc = 0.0;
#pragma unroll 8
        for (int j = 0; j < 512; ++j) acc += (double)A[(long)j * 512 + c] * (double)xl[j];
        yv[c] = (float)acc + T.be[t] * xl[c];
    }
}

// ============ terms + s-kernel fused ============
__global__ __launch_bounds__(512) void k_termsk(const float* __restrict__ WV, const float* __restrict__ V,
                                                float* __restrict__ svec)
{
    __shared__ float tl[520];
    __shared__ float invn[5];
    __shared__ float red[2];
    int tid = threadIdx.x;
    for (int t = tid; t < 520; t += 512) {
        int z = t / 104, d = t - z * 104;
        int j = d >> 3, i = d & 7;
        const float* wp = WV + z * 6656 + j * 512;
        const float* vp = V + z * 4096 + i * 512;
        float acc = 0.0f;
#pragma unroll 8
        for (int k = 0; k < 512; ++k) acc += wp[k] * vp[k];
        tl[t] = acc;
    }
    __syncthreads();
    int w = tid >> 6, lane = tid & 63;
    if (w < 5) {
        float a = tl[w * 104 + lane]; a = a * a;
        if (lane < 40) { float b = tl[w * 104 + 64 + lane]; a += b * b; }
#pragma unroll
        for (int off = 32; off; off >>= 1) a += __shfl_down(a, off);
        if (lane == 0) invn[w] = 1.0f / (sqrtf(a) + 1e-6f);
    }
    __syncthreads();
    float s = 0.0f;
    if (tid < 104) {
        s = 1.0f;
        for (int l = 0; l < 5; ++l) s *= tl[l * 104 + (103 - tid)] * invn[l];
        svec[tid] = s;
    }
    if (tid < 128) {
        float v = (tid < 104) ? s : 0.0f;
#pragma unroll
        for (int off = 32; off; off >>= 1) v += __shfl_down(v, off);
        if ((tid & 63) == 0) red[tid >> 6] = v;
    }
    __syncthreads();
    if (tid == 0) svec[104] = (red[0] + red[1]) * (1.0f / 104.0f);
}

// ============ conv0 (1->H) + stats, bf16 out ============
__global__ void k_conv0(const float* __restrict__ x, const float* __restrict__ w0, const float* __restrict__ b0,
                        unsigned short* __restrict__ y, double* __restrict__ s1g, double* __restrict__ s2g)
{
    int b = blockIdx.x;
    int c = blockIdx.y * 256 + threadIdx.x;
    float w_0 = w0[c * 3 + 0], w_1 = w0[c * 3 + 1], w_2 = w0[c * 3 + 2], bb = b0[c];
    const float* xb = x + b * 104;
    unsigned short* yb = y + (long)b * 104 * 512 + c;
    float xm2 = 0.0f, xm1 = 0.0f;
    float s1 = 0.0f, s2 = 0.0f;
    for (int t = 0; t < 104; ++t) {
        float x0 = xb[t];
        float v = w_0 * xm2 + w_1 * xm1 + w_2 * x0 + bb;
        yb[t * 512] = f2bf(v);
        s1 += v; s2 += v * v;
        xm2 = xm1; xm1 = x0;
    }
    atomicAdd(&s1g[c], (double)s1);
    atomicAdd(&s2g[c], (double)s2);
}

// ============ MFMA conv GEMM: 256x256 block, 128x128/wave, tau-outer ============
__global__ __launch_bounds__(256, 1) void k_convm(
    const unsigned short* __restrict__ act,
    const unsigned short* __restrict__ Wt2,       // [3][512][512] for this layer
    const float* __restrict__ bias,
    const double* __restrict__ STin,
    const float* __restrict__ gam, const float* __restrict__ bet,
    unsigned short* __restrict__ yout,
    double* __restrict__ s1g, double* __restrict__ s2g)
{
    __shared__ __align__(16) unsigned short As[256 * 32];   // 16 KB
    __shared__ __align__(16) unsigned short Bs[256 * 32];   // 16 KB
    __shared__ float SCs[512];
    __shared__ float SHs[512];
    int tid = threadIdx.x;
    int m0 = blockIdx.x * 256, n0 = blockIdx.y * 256;
    int w = tid >> 6, lane = tid & 63;
    int wr = (w >> 1) * 128, wc = (w & 1) * 128;
    int fr = lane & 15, fkb = (lane >> 4) * 8, quad = lane >> 4;

    const double invN = 1.0 / (double)BM;
    for (int c = tid; c < 512; c += 256) {
        double mn = STin[c] * invN;
        double var = STin[512 + c] * invN - mn * mn;
        double rs = 1.0 / sqrt(var + (double)BN_EPS);
        double scd = (double)gam[c] * rs;
        SCs[c] = (float)scd;
        SHs[c] = (float)((double)bet[c] - mn * scd);
    }
    int arow = tid >> 2, ak = (tid & 3) * 8;

    f32x4 acc[8][8];
#pragma unroll
    for (int i = 0; i < 8; ++i)
#pragma unroll
        for (int j = 0; j < 8; ++j) { f32x4 zz = {0.f, 0.f, 0.f, 0.f}; acc[i][j] = zz; }

    for (int tau = 0; tau < 3; ++tau) {
#pragma unroll 1
        for (int s = 0; s < 16; ++s) {
            int ci0 = s * 32;
            __syncthreads();
            // B: async global->LDS, 4 chunks (co = q>>2, k = (q&3)*8)
#pragma unroll
            for (int it = 0; it < 4; ++it) {
                int q = it * 256 + tid;
                int co = q >> 2, kq = (q & 3) * 8;
                gld16(Wt2 + ((long)tau << 18) + ((long)(n0 + co) << 9) + ci0 + kq, &Bs[q * 8]);
            }
            // A: VGPR load + BN+ReLU + causal zero + ds_write
            int cb = ci0 + ak;
            float4 s0 = *(const float4*)&SCs[cb], s1v = *(const float4*)&SCs[cb + 4];
            float4 h0 = *(const float4*)&SHs[cb], h1v = *(const float4*)&SHs[cb + 4];
            float ss[8] = {s0.x, s0.y, s0.z, s0.w, s1v.x, s1v.y, s1v.z, s1v.w};
            float hh[8] = {h0.x, h0.y, h0.z, h0.w, h1v.x, h1v.y, h1v.z, h1v.w};
#pragma unroll
            for (int it = 0; it < 4; ++it) {
                int row = it * 64 + arow;
                int gr = m0 + row;
                int t = gr % 104;
                bool val = (t + tau >= 2);
                uint4 v = make_uint4(0u, 0u, 0u, 0u);
                if (val) v = *(const uint4*)(act + (long)(gr + tau - 2) * 512 + ci0 + ak);
                unsigned short u[8];
                u[0] = (unsigned short)(v.x & 0xFFFF); u[1] = (unsigned short)(v.x >> 16);
                u[2] = (unsigned short)(v.y & 0xFFFF); u[3] = (unsigned short)(v.y >> 16);
                u[4] = (unsigned short)(v.z & 0xFFFF); u[5] = (unsigned short)(v.z >> 16);
                u[6] = (unsigned short)(v.w & 0xFFFF); u[7] = (unsigned short)(v.w >> 16);
                unsigned short o[8];
#pragma unroll
                for (int q = 0; q < 8; ++q)
                    o[q] = val ? f2bf(fmaxf(fmaf(bf2f(u[q]), ss[q], hh[q]), 0.0f)) : (unsigned short)0;
                uint4 pk;
                pk.x = (uint32_t)o[0] | ((uint32_t)o[1] << 16);
                pk.y = (uint32_t)o[2] | ((uint32_t)o[3] << 16);
                pk.z = (uint32_t)o[4] | ((uint32_t)o[5] << 16);
                pk.w = (uint32_t)o[6] | ((uint32_t)o[7] << 16);
                *(uint4*)&As[(row << 5) + ak] = pk;
            }
            __syncthreads();
            bf16x8 af[8], bf[8];
#pragma unroll
            for (int i = 0; i < 8; ++i)
                af[i] = *(const bf16x8*)&As[(wr + i * 16 + fr) * 32 + fkb];
#pragma unroll
            for (int j = 0; j < 8; ++j)
                bf[j] = *(const bf16x8*)&Bs[(wc + j * 16 + fr) * 32 + fkb];
#pragma unroll
            for (int i = 0; i < 8; ++i)
#pragma unroll
                for (int j = 0; j < 8; ++j)
                    acc[i][j] = __builtin_amdgcn_mfma_f32_16x16x32_bf16(af[i], bf[j], acc[i][j], 0, 0, 0);
        }
    }
    // epilogue: bias, bf16 store, per-channel stats
    float bcol[8], s1[8], s2[8];
#pragma unroll
    for (int j = 0; j < 8; ++j) {
        bcol[j] = bias[n0 + wc + j * 16 + fr];
        s1[j] = 0.f; s2[j] = 0.f;
    }
#pragma unroll
    for (int i = 0; i < 8; ++i) {
        int rbase = m0 + wr + i * 16 + quad * 4;
#pragma unroll
        for (int j = 0; j < 8; ++j) {
            int col = n0 + wc + j * 16 + fr;
#pragma unroll
            for (int r = 0; r < 4; ++r) {
                float v = acc[i][j][r] + bcol[j];
                yout[(long)(rbase + r) * 512 + col] = f2bf(v);
                s1[j] += v; s2[j] += v * v;
            }
        }
    }
#pragma unroll
    for (int j = 0; j < 8; ++j) {
        s1[j] += __shfl_xor(s1[j], 16); s1[j] += __shfl_xor(s1[j], 32);
        s2[j] += __shfl_xor(s2[j], 16); s2[j] += __shfl_xor(s2[j], 32);
    }
    __syncthreads();
    float* st = (float*)As;   // [s1: 2 slots x 256][s2: 2 slots x 256]
    int slot = w >> 1;
    if (lane < 16) {
#pragma unroll
        for (int j = 0; j < 8; ++j) {
            st[slot * 256 + wc + j * 16 + lane] = s1[j];
            st[512 + slot * 256 + wc + j * 16 + lane] = s2[j];
        }
    }
    __syncthreads();
    {
        float a = st[tid] + st[256 + tid];
        float b = st[512 + tid] + st[768 + tid];
        atomicAdd(&s1g[n0 + tid], (double)a);
        atomicAdd(&s2g[n0 + tid], (double)b);
    }
}

// ============ pool ============
__global__ void k_pool(const unsigned short* __restrict__ y4, const double* __restrict__ ST4,
                       const float* __restrict__ gam, const float* __restrict__ bet,
                       const float* __restrict__ svec, float* __restrict__ g)
{
    __shared__ float sl[104];
    int b = blockIdx.x;
    int c = blockIdx.y * 256 + threadIdx.x;
    if (threadIdx.x < 104) sl[threadIdx.x] = svec[threadIdx.x];
    __syncthreads();
    const double invN = 1.0 / (double)BM;
    double mn = ST4[c] * invN;
    double var = ST4[512 + c] * invN - mn * mn;
    double rs = 1.0 / sqrt(var + (double)BN_EPS);
    double scd = (double)gam[c] * rs;
    float sc = (float)scd, sh = (float)((double)bet[c] - mn * scd);
    int he = c & ~1;
    float div = expf((float)he * (-0.017988946039015984f));
    float acc = 0.0f;
    const unsigned short* yb = y4 + (long)b * 104 * 512 + c;
    for (int t = 0; t < 104; ++t) {
        float v = bf2f(yb[t * 512]);
        float hn = fmaxf(fmaf(v, sc, sh), 0.0f);
        float arg = (float)t * div;
        float pe = (c & 1) ? cosf(arg) : sinf(arg);
        acc += sl[t] * (hn + pe);
    }
    g[(long)b * 512 + c] = acc * (1.0f / 104.0f);
}

// ============ dual 512x512 transpose ============
__global__ void k_t512(const float* __restrict__ in0, float* __restrict__ out0,
                       const float* __restrict__ in1, float* __restrict__ out1)
{
    __shared__ float tile[64 * 68];
    const float* in = blockIdx.z ? in1 : in0;
    float* outp = blockIdx.z ? out1 : out0;
    int bx = blockIdx.x, by = blockIdx.y;
    int tid = threadIdx.x;
    for (int it = 0; it < 4; ++it) {
        int s = it * 256 + tid;
        int r = s >> 4, c4 = (s & 15) * 4;
        *(float4*)&tile[r * 68 + c4] = *(const float4*)&in[(long)(bx * 64 + r) * 512 + by * 64 + c4];
    }
    __syncthreads();
    for (int it = 0; it < 4; ++it) {
        int s = it * 256 + tid;
        int r = s >> 4, c4 = (s & 15) * 4;
        float4 v;
        v.x = tile[(c4 + 0) * 68 + r];
        v.y = tile[(c4 + 1) * 68 + r];
        v.z = tile[(c4 + 2) * 68 + r];
        v.w = tile[(c4 + 3) * 68 + r];
        *(float4*)&outp[(long)(by * 64 + r) * 512 + bx * 64 + c4] = v;
    }
}

// ============ head matmul (mode 5: +b*sbar; mode 8: +b, fp64 col stats) ============
__global__ __launch_bounds__(256) void k_mm(
    const float* __restrict__ A, const float* __restrict__ Bm, float* __restrict__ C,
    int mode, const float* __restrict__ aux, const float* __restrict__ aux2,
    double* __restrict__ st1, double* __restrict__ st2)
{
    __shared__ float sm[2 * 32 * 68];
    float* As = sm;
    float* Bs = sm + 32 * 68;
    int m0 = blockIdx.x * 64, n0 = blockIdx.y * 64;
    int tid = threadIdx.x;
    int tx = tid & 15, ty = tid >> 4;
    float acc[4][4] = {};
    for (int k0 = 0; k0 < 512; k0 += 32) {
        __syncthreads();
#pragma unroll
        for (int it = 0; it < 2; ++it) {
            int s = it * 256 + tid;
            int mm = s >> 3, k4 = (s & 7) * 4;
            float4 v = *(const float4*)&A[(long)(m0 + mm) * 512 + k0 + k4];
            As[(k4 + 0) * 68 + mm] = v.x;
            As[(k4 + 1) * 68 + mm] = v.y;
            As[(k4 + 2) * 68 + mm] = v.z;
            As[(k4 + 3) * 68 + mm] = v.w;
        }
#pragma unroll
        for (int it = 0; it < 2; ++it) {
            int s = it * 256 + tid;
            int kk = s >> 4, n4 = (s & 15) * 4;
            *(float4*)&Bs[kk * 68 + n4] = *(const float4*)&Bm[(long)(k0 + kk) * 512 + n0 + n4];
        }
        __syncthreads();
#pragma unroll 8
        for (int kk = 0; kk < 32; ++kk) {
            float4 a = *(const float4*)&As[kk * 68 + ty * 4];
            float4 b = *(const float4*)&Bs[kk * 68 + tx * 4];
            float av[4] = {a.x, a.y, a.z, a.w};
            float bv[4] = {b.x, b.y, b.z, b.w};
#pragma unroll
            for (int i = 0; i < 4; ++i)
#pragma unroll
                for (int j = 0; j < 4; ++j)
                    acc[i][j] = fmaf(av[i], bv[j], acc[i][j]);
        }
    }
    float sc2 = (mode == 5) ? aux2[0] : 0.0f;
    float cs1[4] = {0, 0, 0, 0}, cs2[4] = {0, 0, 0, 0};
#pragma unroll
    for (int i = 0; i < 4; ++i) {
        int col0 = n0 + tx * 4;
        long base = (long)(m0 + ty * 4 + i) * 512 + col0;
        float v[4];
#pragma unroll
        for (int j = 0; j < 4; ++j) v[j] = acc[i][j];
        if (mode == 5) {
            for (int j = 0; j < 4; ++j) v[j] += aux[col0 + j] * sc2;
        } else {
            for (int j = 0; j < 4; ++j) {
                v[j] += aux[col0 + j];
                cs1[j] += v[j]; cs2[j] += v[j] * v[j];
            }
        }
        *(float4*)&C[base] = make_float4(v[0], v[1], v[2], v[3]);
    }
    if (mode == 8) {
        __syncthreads();
        float* s1s = sm;
        float* s2s = sm + 1024;
#pragma unroll
        for (int j = 0; j < 4; ++j) {
            s1s[ty * 64 + tx * 4 + j] = cs1[j];
            s2s[ty * 64 + tx * 4 + j] = cs2[j];
        }
        __syncthreads();
        if (tid < 64) {
            double a = 0.0, b = 0.0;
#pragma unroll
            for (int t = 0; t < 16; ++t) { a += s1s[t * 64 + tid]; b += s2s[t * 64 + tid]; }
            atomicAdd(&st1[n0 + tid], a);
            atomicAdd(&st2[n0 + tid], b);
        }
    }
}

// ============ BN(batch) -> exact GELU -> fc2 ============
__global__ __launch_bounds__(256) void k_final(const float* __restrict__ zin, const double* __restrict__ st,
                                               const float* __restrict__ gam, const float* __restrict__ bet,
                                               const float* __restrict__ w2, const float* __restrict__ b2,
                                               float* __restrict__ outp)
{
    __shared__ float red[256];
    int b = blockIdx.x, tid = threadIdx.x;
    int oo[2] = { tid, tid + 256 };
    float gv[2];
#pragma unroll
    for (int q = 0; q < 2; ++q) {
        int o = oo[q];
        double m = st[o] * (1.0 / 512.0);
        double var = st[512 + o] * (1.0 / 512.0) - m * m;
        double rs = 1.0 / sqrt(var + (double)BN_EPS);
        float xn = (float)(((double)zin[(long)b * 512 + o] - m) * rs * (double)gam[o] + (double)bet[o]);
        gv[q] = 0.5f * xn * (1.0f + erff(xn * 0.70710678118654752f));
    }
    for (int n = 0; n < 5; ++n) {
        float p = gv[0] * w2[n * 512 + oo[0]] + gv[1] * w2[n * 512 + oo[1]];
        red[tid] = p;
        __syncthreads();
        for (int off = 128; off; off >>= 1) { if (tid < off) red[tid] += red[tid + off]; __syncthreads(); }
        if (tid == 0) outp[b * 5 + n] = red[0] + b2[n];
        __syncthreads();
    }
}

// ===================== host side =====================
extern "C" void kernel_launch(void* const* d_in, const int* in_sizes, int n_in,
                              void* d_out, int out_size, void* d_ws, size_t ws_size,
                              hipStream_t stream)
{
    (void)in_sizes; (void)n_in; (void)out_size;
    const float* x       = (const float*)d_in[0];
    const float* conv_w0 = (const float*)d_in[1];
    const float* conv_b0 = (const float*)d_in[2];
    const float* conv_w  = (const float*)d_in[3];
    const float* conv_b  = (const float*)d_in[4];
    const float* bn_g    = (const float*)d_in[5];
    const float* bn_b    = (const float*)d_in[6];
    const float* proj_w  = (const float*)d_in[7];
    const float* proj_b  = (const float*)d_in[8];
    const float* A_all   = (const float*)d_in[9];
    const float* B_all   = (const float*)d_in[10];
    const float* C_all   = (const float*)d_in[11];
    const float* fc1_w   = (const float*)d_in[12];
    const float* fc1_b   = (const float*)d_in[13];
    const float* fbn_g   = (const float*)d_in[14];
    const float* fbn_b   = (const float*)d_in[15];
    const float* fc2_w   = (const float*)d_in[16];
    const float* fc2_b   = (const float*)d_in[17];
    float* outp = (float*)d_out;
    char* ws = (char*)d_ws;
    if (ws_size < WS_NEED) { printf("ws too small: %zu < %zu\n", ws_size, WS_NEED); return; }

    unsigned short* YB0 = (unsigned short*)(ws + OFF_YB0);
    unsigned short* YB1 = (unsigned short*)(ws + OFF_YB1);
    unsigned short* WT2 = (unsigned short*)(ws + OFF_WT2);
    float* XP   = (float*)(ws + OFF_XP);
    float* MW   = (float*)(ws + OFF_MW);
    float* ROWT = (float*)(ws + OFF_ROWT);
    float* COLS1= (float*)(ws + OFF_COLS1);
    float* COLS2= (float*)(ws + OFF_COLS2);
    float* PIVA = (float*)(ws + OFF_PIVA);
    float* PIVB = (float*)(ws + OFF_PIVB);
    float* RU   = (float*)(ws + OFF_RU);
    float* PJT  = (float*)(ws + OFF_PJT);
    float* F1T  = (float*)(ws + OFF_F1T);
    float* G    = (float*)(ws + OFF_G);
    float* POOL = (float*)(ws + OFF_POOL);
    float* Zb   = (float*)(ws + OFF_Z);
    double* ST  = (double*)(ws + OFF_ST);
    float* V    = (float*)(ws + OFF_V);
    float* WV   = (float*)(ws + OFF_WV);
    float* SVEC = (float*)(ws + OFF_SVEC);

    hipMemsetAsync(ws + OFF_ST, 0, 49152, stream);

    // ---- front: conv weights->bf16 + build(X,S,COLS0,W0) + inv0 ----
    k_front<<<7173, 256, 0, stream>>>(conv_w, WT2, A_all, XP, MW, COLS1, C_all, WV, PIVA);

    // ---- X powers: X2; X3,X4; X5..X8 (packed) ----
    auto XPo = [](int p) { return (long)(OFF_XP + (size_t)(p - 1) * SZ_M5); };
    {
        MMT T = {};
        T.a[0] = XPo(1); T.b[0] = XPo(1); T.c[0] = XPo(2);
        k_mmP<<<dim3(8, 8, 5), 256, 0, stream>>>(ws, T);
    }
    {
        MMT T = {};
        T.a[0] = XPo(2); T.b[0] = XPo(1); T.c[0] = XPo(3);
        T.a[1] = XPo(2); T.b[1] = XPo(2); T.c[1] = XPo(4);
        k_mmP<<<dim3(8, 8, 10), 256, 0, stream>>>(ws, T);
    }
    {
        MMT T = {};
        T.a[0] = XPo(4); T.b[0] = XPo(1); T.c[0] = XPo(5);
        T.a[1] = XPo(4); T.b[1] = XPo(2); T.c[1] = XPo(6);
        T.a[2] = XPo(4); T.b[2] = XPo(3); T.c[2] = XPo(7);
        T.a[3] = XPo(4); T.b[3] = XPo(4); T.c[3] = XPo(8);
        k_mmP<<<dim3(8, 8, 20), 256, 0, stream>>>(ws, T);
    }
    // ---- poly: E_k = A_bar^(2^k) - I, k=0..5 (overwrite XP1..XP6) ----
    {
        PolyC P;
        for (int k = 0; k < 6; ++k) {
            double f = (double)(1 << k);
            double fp = 1.0, fact = 1.0;
            for (int p = 1; p <= 8; ++p) { fp *= f; fact *= (double)p; P.c[k][p - 1] = (float)(fp / fact); }
        }
        k_poly<<<5120, 256, 0, stream>>>(XP, P);
    }
    // ---- u = 0.1 * E0 * Bv  (into V0) ----
    k_matvecA<<<dim3(512, 5), 64, 0, stream>>>(XP, 262144, B_all, 512, V, 4096, 0.1f);
    // ---- GJ solve S x = u (augmented, blocked, fused next-inverse) ----
    for (int p = 0; p < 8; ++p) {
        const float* Pc = (p & 1) ? PIVB : PIVA;
        float* Pn       = (p & 1) ? PIVA : PIVB;
        const float* Cc = (p & 1) ? COLS2 : COLS1;
        float* Cn       = (p & 1) ? COLS1 : COLS2;
        k_rowscale<<<dim3(8 - p, 1, 5), 256, 0, stream>>>(MW, Pc, V, ROWT, RU, p);
        k_elim2<<<dim3(8, 8 - p, 5), 256, 0, stream>>>(MW, Cc, Cn, ROWT, RU, V, Pn, p);
    }
    // ---- V/W chains (E-matrices, +x) ----
    auto Eo = [](int k) { return (long)(OFF_XP + (size_t)k * SZ_M5); };
    auto Voff = [](int i) { return (long)(OFF_V + (size_t)i * 2048); };
    auto Woff = [](int j) { return (long)(OFF_WV + (size_t)j * 2048); };
    {
        VWT T = {};
        T.a[0] = Eo(0); T.x[0] = Voff(0); T.y[0] = Voff(1); T.al[0] = 1; T.be[0] = 1; T.ty[0] = 0;
        T.a[1] = Eo(3); T.x[1] = Woff(0); T.y[1] = Woff(1); T.be[1] = 1; T.ty[1] = 1;
        k_vw<<<dim3(8, 5, 2), 64, 0, stream>>>(ws, T);
    }
    {
        VWT T = {};
        T.a[0] = Eo(1); T.x[0] = Voff(0); T.y[0] = Voff(2); T.al[0] = 1; T.be[0] = 1; T.ty[0] = 0;
        T.a[1] = Eo(1); T.x[1] = Voff(1); T.y[1] = Voff(3); T.al[1] = 1; T.be[1] = 1; T.ty[1] = 0;
        T.a[2] = Eo(4); T.x[2] = Woff(0); T.y[2] = Woff(2); T.be[2] = 1; T.ty[2] = 1;
        T.a[3] = Eo(4); T.x[3] = Woff(1); T.y[3] = Woff(3); T.be[3] = 1; T.ty[3] = 1;
        k_vw<<<dim3(8, 5, 4), 64, 0, stream>>>(ws, T);
    }
    {
        VWT T = {};
        for (int i = 0; i < 4; ++i) {
            T.a[i] = Eo(2); T.x[i] = Voff(i); T.y[i] = Voff(4 + i); T.al[i] = 1; T.be[i] = 1; T.ty[i] = 0;
            T.a[4 + i] = Eo(5); T.x[4 + i] = Woff(i); T.y[4 + i] = Woff(4 + i); T.be[4 + i] = 1; T.ty[4 + i] = 1;
        }
        k_vw<<<dim3(8, 5, 8), 64, 0, stream>>>(ws, T);
    }
    {
        VWT T = {};
        for (int i = 0; i < 4; ++i) {
            T.a[i] = Eo(5); T.x[i] = Woff(4 + i); T.y[i] = Woff(8 + i); T.be[i] = 1; T.ty[i] = 1;
        }
        k_vw<<<dim3(8, 5, 4), 64, 0, stream>>>(ws, T);
    }
    {
        VWT T = {};
        T.a[0] = Eo(5); T.x[0] = Woff(8); T.y[0] = Woff(12); T.be[0] = 1; T.ty[0] = 1;
        k_vw<<<dim3(8, 5, 1), 64, 0, stream>>>(ws, T);
    }
    k_termsk<<<1, 512, 0, stream>>>(WV, V, SVEC);

    // ---- conv chain (overlay region now dead; YB0/YB1 reused) ----
    k_conv0<<<dim3(512, 2), 256, 0, stream>>>(x, conv_w0, conv_b0, YB0, ST, ST + 512);
    for (int l = 1; l <= 4; ++l) {
        unsigned short* inb  = (l & 1) ? YB0 : YB1;
        unsigned short* outb = (l & 1) ? YB1 : YB0;
        k_convm<<<dim3(208, 2), 256, 0, stream>>>(inb, WT2 + (size_t)(l - 1) * 3 * 262144,
                                                  conv_b + (l - 1) * 512,
                                                  ST + (l - 1) * 1024, bn_g + (l - 1) * 512, bn_b + (l - 1) * 512,
                                                  outb, ST + l * 1024, ST + l * 1024 + 512);
    }
    k_pool<<<dim3(512, 2), 256, 0, stream>>>(YB0, ST + 4 * 1024, bn_g + 4 * 512, bn_b + 4 * 512, SVEC, G);

    // ---- head ----
    k_t512<<<dim3(8, 8, 2), 256, 0, stream>>>(proj_w, PJT, fc1_w, F1T);
    k_mm<<<dim3(8, 8), 256, 0, stream>>>(G, PJT, POOL, 5, proj_b, SVEC + 104, nullptr, nullptr);
    k_mm<<<dim3(8, 8), 256, 0, stream>>>(POOL, F1T, Zb, 8, fc1_b, nullptr, ST + 5 * 1024, ST + 5 * 1024 + 512);
    k_final<<<512, 256, 0, stream>>>(Zb, ST + 5 * 1024, fbn_g, fbn_b, fc2_w, fc2_b, outp);
}